// Round 7
// baseline (169.459 us; speedup 1.0000x reference)
//
#include <hip/hip_runtime.h>
#include <math.h>

// Problem constants (B, N, D) = (256, 128, 128)
#define B_    256
#define N_    128
#define MAXP  30
#define OTHER_ 35
#define CIN1  131      // real channels into conv1
#define NIDX  381      // 3*(N-1)

// conv K-geometry: KPAD per kk-region, 3 regions; fragment k-steps of 32
#define KPAD1 160
#define KPAD2 256
#define KPAD3 128
// weight-pack element counts: KSTEPS*4wo*SUB*512
#define S_IDX (B_ * NIDX)
#define S_P1  (15 * 4 * 4 * 512)   // 122880
#define S_P2  (24 * 4 * 2 * 512)   // 98304
#define S_P3  (12 * 4 * 1 * 512)   // 24576

typedef short short8 __attribute__((ext_vector_type(8)));
typedef float f32x4 __attribute__((ext_vector_type(4)));

// RNE split of f32 into hi/lo bf16 (bit patterns as short)
__device__ inline void split1(float v, short& h, short& l) {
  unsigned u = __float_as_uint(v);
  unsigned hb = (u + 0x7fffu + ((u >> 16) & 1u)) >> 16;
  float fh = __uint_as_float(hb << 16);
  float r = v - fh;
  unsigned u2 = __float_as_uint(r);
  unsigned lb = (u2 + 0x7fffu + ((u2 >> 16) & 1u)) >> 16;
  h = (short)hb;
  l = (short)lb;
}

// ---------------------------------------------------------------------------
// Weight pack: element l -> fragment layout [gks][wo][su][lane][e], value
// w[oc][ch][kk] split into hi/lo bf16. oc=(wo*SUB+su)*16+(lane&15),
// ctot=gks*32+((lane>>4)&3)*8+e, kk=ctot/KPAD, ch=ctot%KPAD (0 if ch>=KREAL).
// ---------------------------------------------------------------------------
template <int KREAL, int KPAD, int SUB>
__device__ inline void packw(int l, const float* __restrict__ w,
                             short* __restrict__ oh, short* __restrict__ ol) {
  const int e = l & 7;
  const int lane = (l >> 3) & 63;
  const int x = l >> 9;
  const int su = x % SUB;
  const int y = x / SUB;
  const int wo = y & 3;
  const int gks = y >> 2;
  const int oc = (wo * SUB + su) * 16 + (lane & 15);
  const int ctot = gks * 32 + ((lane >> 4) & 3) * 8 + e;
  const int kk = ctot / KPAD;
  const int ch = ctot - kk * KPAD;
  const float v = (ch < KREAL) ? w[(oc * KREAL + ch) * 3 + kk] : 0.f;
  short h, lo;
  split1(v, h, lo);
  oh[l] = h;
  ol[l] = lo;
}

__global__ __launch_bounds__(256) void prep_kernel(
    const void* __restrict__ rawIdx, int* __restrict__ idx32,
    const float* __restrict__ w1, short* __restrict__ w1h, short* __restrict__ w1l,
    const float* __restrict__ w2, short* __restrict__ w2h, short* __restrict__ w2l,
    const float* __restrict__ w3, short* __restrict__ w3h, short* __restrict__ w3l) {
  const int gid = blockIdx.x * 256 + threadIdx.x;
  if (gid < S_IDX) {
    // int64 LE view is (v,0,v,0,...) with v in [0,128)
    const int* r32 = (const int*)rawIdx;
    const int lane = threadIdx.x & 63;
    const int lo = r32[2 * lane];
    const int hi = r32[2 * lane + 1];
    const bool ok = (hi == 0 && lo >= 0 && lo < N_);
    const bool is64 = __all(ok);
    idx32[gid] = is64 ? (int)((const long long*)rawIdx)[gid] : r32[gid];
  } else if (gid < S_IDX + S_P1) {
    packw<131, KPAD1, 4>(gid - S_IDX, w1, w1h, w1l);
  } else if (gid < S_IDX + S_P1 + S_P2) {
    packw<256, KPAD2, 2>(gid - (S_IDX + S_P1), w2, w2h, w2l);
  } else if (gid < S_IDX + S_P1 + S_P2 + S_P3) {
    packw<128, KPAD3, 1>(gid - (S_IDX + S_P1 + S_P2), w3, w3h, w3l);
  }
}

// ---------------------------------------------------------------------------
// Embedding + collate v2: block = one batch. Stage feature[b] (128x128 f32)
// into LDS coalesced (row stride 133 words, odd mod 32 -> conflict-free
// column reads), then per-node work reads LDS only. Output stride 160.
// ---------------------------------------------------------------------------
__global__ __launch_bounds__(512) void embed_kernel(
    const float* __restrict__ feature,
    const float* __restrict__ col_embed,   // (200,32)
    const float* __restrict__ op_embed,    // (20,32)
    float* __restrict__ collate) {
  __shared__ float feat[128 * 133];
  const int b = blockIdx.x;
  const int tid = threadIdx.x;
  const float* fb = feature + (size_t)b * 16384;

#pragma unroll
  for (int it = 0; it < 8; ++it) {
    const int t = it * 512 + tid;
    const int d = t >> 5;
    const int c4 = (t & 31) * 4;
    const float4 v = *reinterpret_cast<const float4*>(&fb[d * 128 + c4]);
    float* p = &feat[d * 133 + c4];
    p[0] = v.x; p[1] = v.y; p[2] = v.z; p[3] = v.w;
  }
  __syncthreads();

  const int wv = tid >> 6;
  const int lane = tid & 63;
  const float* tp = (lane < 32) ? col_embed : op_embed;
  const int cl = lane & 31;

  for (int ni = 0; ni < 16; ++ni) {
    const int n = wv * 16 + ni;
    int civ = 0, oiv = 0;
    if (lane < MAXP) civ = (int)feat[(OTHER_ + lane) * 133 + n];
    if (lane >= 32 && lane < 32 + MAXP) oiv = (int)feat[(OTHER_ + MAXP + (lane - 32)) * 133 + n];
    const int L = (int)feat[95 * 133 + n];

    float acc = 0.f;
    for (int i = 0; i < L; ++i) {
      const int cv = __shfl(civ, i);
      const int ov = __shfl(oiv, 32 + i);
      const int row = (lane < 32) ? cv : ov;
      acc += tp[row * 32 + cl];
    }

    float* out = collate + ((size_t)b * 128 + n) * KPAD1;
    out[35 + lane] = acc;
    if (lane < 35) out[lane] = feat[lane * 133 + n];
    if (lane < 32) out[99 + lane] = feat[(96 + lane) * 133 + n];
    if (lane < 29) out[131 + lane] = 0.f;   // pad channels
  }
}

// ---------------------------------------------------------------------------
// MFMA tree conv v2: block = one batch (grid 256), 512 threads = 8 waves
// (wj 0..1) x (wo 0..3); wave = j in [wj*64,+64) x oc [(wo*SUB)*16,+SUB*16).
// X staged as bf16 hi/lo in LDS with ODD-GRANULE row stride (CINP/8 odd ->
// random gather rows spread over all 32 banks). K split into NSTG stages of
// STG_CH channels (LDS <= ~71 KB -> 2 blocks/CU); acc carries across stages.
// Weights pre-packed in fragment order (16B/lane coalesced L2 loads).
// 3 MFMAs per kstep: xh*wh + xl*wh + xh*wl. Epilogue: bias, zero col j=0,
// f64 stats {S,Q} -> statsOut[b].
// ---------------------------------------------------------------------------
template <int KPAD, int SUB, bool NORM_IN, int CINP, int NSTG, int STG_CH>
__global__ __launch_bounds__(512, 4) void convm_kernel(
    const float* __restrict__ X,        // (B,128,KPAD) node-major f32
    const int* __restrict__ idx,        // (B,381)
    const short* __restrict__ wH, const short* __restrict__ wL,
    const float* __restrict__ bias,     // (COUT)
    const double* __restrict__ statsIn, // (B,2) {S,Q} or null
    float* __restrict__ Y,              // (B,128,COUT)
    double* __restrict__ statsOut) {    // (B,2)
  constexpr int KPS = KPAD / 32;
  constexpr int COUT = SUB * 64;
  constexpr int JT = 4;

  __shared__ short xhi[128 * CINP];
  __shared__ short xlo[128 * CINP];
  __shared__ int nb_s[NIDX];
  __shared__ double red[16];

  const int b = blockIdx.x;
  const int tid = threadIdx.x;
  const int lane = tid & 63;
  const int w = tid >> 6;
  const int wj = w >> 2;           // 0..1
  const int wo = w & 3;            // 0..3
  const int grp = (lane >> 4) & 3;

  float mean = 0.f, inv = 1.f;
  if (NORM_IN) {
    const double S = statsIn[b * 2];
    const double Q = statsIn[b * 2 + 1];
    const double cnt = (double)KPAD * 128.0;
    const double m = S / cnt;
    double var = (Q - S * S / cnt) / (cnt - 1.0);
    if (var < 0.0) var = 0.0;
    mean = (float)m;
    inv = (float)(1.0 / (sqrt(var) + 1e-5));
  }

  const float* __restrict__ Xb = X + (size_t)b * (128 * KPAD);
  const short8* __restrict__ wH8 = (const short8*)wH;
  const short8* __restrict__ wL8 = (const short8*)wL;

  int nbr[JT][3];
  f32x4 acc[JT][SUB];
#pragma unroll
  for (int jt = 0; jt < JT; ++jt)
#pragma unroll
    for (int su = 0; su < SUB; ++su) {
      acc[jt][su][0] = 0.f; acc[jt][su][1] = 0.f;
      acc[jt][su][2] = 0.f; acc[jt][su][3] = 0.f;
    }

#pragma unroll
  for (int s = 0; s < NSTG; ++s) {
    const int chb = s * STG_CH;
    const int chn = (KPAD - chb < STG_CH) ? (KPAD - chb) : STG_CH;
    const int PKs = chn / 8;
    if (s > 0) __syncthreads();
    for (int t = tid; t < 128 * PKs; t += 512) {
      const int n = t / PKs;
      const int ch0 = chb + (t - n * PKs) * 8;
      const float4 a0 = *reinterpret_cast<const float4*>(&Xb[n * KPAD + ch0]);
      const float4 a1 = *reinterpret_cast<const float4*>(&Xb[n * KPAD + ch0 + 4]);
      float vv[8] = {a0.x, a0.y, a0.z, a0.w, a1.x, a1.y, a1.z, a1.w};
      short8 h8, l8;
#pragma unroll
      for (int i = 0; i < 8; ++i) {
        float v = vv[i];
        if (NORM_IN) {
          v = (v - mean) * inv;
          v = (v > 0.f) ? v : 0.01f * v;
        }
        short h, l;
        split1(v, h, l);
        h8[i] = h;
        l8[i] = l;
      }
      const int ei = n * CINP + (ch0 - chb);
      *reinterpret_cast<short8*>(&xhi[ei]) = h8;
      *reinterpret_cast<short8*>(&xlo[ei]) = l8;
    }
    if (s == 0 && tid < NIDX) nb_s[tid] = idx[b * NIDX + tid];
    __syncthreads();

    if (s == 0) {
#pragma unroll
      for (int jt = 0; jt < JT; ++jt) {
        const int j = wj * 64 + jt * 16 + (lane & 15);
#pragma unroll
        for (int kk = 0; kk < 3; ++kk)
          nbr[jt][kk] = (j > 0) ? nb_s[(j - 1) * 3 + kk] : 0;
      }
    }

    const int ks_lo = chb / 32;
    const int ks_hi = (chb + chn) / 32;
#pragma unroll
    for (int kk = 0; kk < 3; ++kk) {
#pragma unroll 2
      for (int ks = ks_lo; ks < ks_hi; ++ks) {
        const int gks = kk * KPS + ks;
        short8 bh[SUB], bl[SUB];
#pragma unroll
        for (int su = 0; su < SUB; ++su) {
          const int wi = ((gks * 4 + wo) * SUB + su) * 64 + lane;
          bh[su] = wH8[wi];
          bl[su] = wL8[wi];
        }
        const int ch_off = ks * 32 - chb + grp * 8;
#pragma unroll
        for (int jt = 0; jt < JT; ++jt) {
          const int ei = nbr[jt][kk] * CINP + ch_off;
          const short8 ah = *reinterpret_cast<const short8*>(&xhi[ei]);
          const short8 al = *reinterpret_cast<const short8*>(&xlo[ei]);
#pragma unroll
          for (int su = 0; su < SUB; ++su) {
            acc[jt][su] = __builtin_amdgcn_mfma_f32_16x16x32_bf16(ah, bh[su], acc[jt][su], 0, 0, 0);
            acc[jt][su] = __builtin_amdgcn_mfma_f32_16x16x32_bf16(al, bh[su], acc[jt][su], 0, 0, 0);
            acc[jt][su] = __builtin_amdgcn_mfma_f32_16x16x32_bf16(ah, bl[su], acc[jt][su], 0, 0, 0);
          }
        }
      }
    }
  }

  // ---- epilogue: bias, zero col, store, f64 stats ----
  double s_sum = 0.0, s_sq = 0.0;
#pragma unroll
  for (int su = 0; su < SUB; ++su) {
    const int oc = (wo * SUB + su) * 16 + (lane & 15);
    const float bv = bias[oc];
#pragma unroll
    for (int jt = 0; jt < JT; ++jt) {
#pragma unroll
      for (int r = 0; r < 4; ++r) {
        const int j = wj * 64 + jt * 16 + grp * 4 + r;
        const float val = (j > 0) ? acc[jt][su][r] + bv : 0.f;
        Y[((size_t)b * 128 + j) * COUT + oc] = val;
        s_sum += (double)val;
        s_sq += (double)val * (double)val;
      }
    }
  }

#pragma unroll
  for (int o = 32; o > 0; o >>= 1) {
    s_sum += __shfl_down(s_sum, o, 64);
    s_sq  += __shfl_down(s_sq, o, 64);
  }
  if (lane == 0) { red[w * 2] = s_sum; red[w * 2 + 1] = s_sq; }
  __syncthreads();
  if (tid == 0) {
    double S = 0.0, Q = 0.0;
#pragma unroll
    for (int i = 0; i < 8; ++i) { S += red[i * 2]; Q += red[i * 2 + 1]; }
    statsOut[b * 2] = S;
    statsOut[b * 2 + 1] = Q;
  }
}

// ---------------------------------------------------------------------------
// Final: combine conv3 stats, normalize, maxpool, 2-layer MLP.
// ---------------------------------------------------------------------------
__global__ __launch_bounds__(64) void final_kernel(
    const float* __restrict__ Y3,      // (B,128,64)
    const double* __restrict__ st,     // (B,2)
    const float* __restrict__ fw1,     // (32,64)
    const float* __restrict__ fb1,     // (32)
    const float* __restrict__ fw2,     // (1,32)
    const float* __restrict__ fb2,     // (1)
    float* __restrict__ out) {
  const int b = blockIdx.x;
  const int lane = threadIdx.x;

  const double S = st[b * 2];
  const double Q = st[b * 2 + 1];
  const double cnt = 64.0 * 128.0;
  const double m = S / cnt;
  double var = (Q - S * S / cnt) / (cnt - 1.0);
  if (var < 0.0) var = 0.0;
  const float mean = (float)m;
  const float inv = (float)(1.0 / (sqrt(var) + 1e-5));

  const float* Yb = Y3 + (size_t)b * 128 * 64;
  float mx = -3.4e38f;
  for (int n = 0; n < 128; ++n) {
    const float v = (Yb[n * 64 + lane] - mean) * inv;
    mx = fmaxf(mx, v);
  }
  __shared__ float pooled[64];
  __shared__ float hs[32];
  pooled[lane] = mx;
  __syncthreads();
  if (lane < 32) {
    float a = fb1[lane];
    for (int c = 0; c < 64; ++c) a = fmaf(pooled[c], fw1[lane * 64 + c], a);
    hs[lane] = fmaxf(a, 0.f);
  }
  __syncthreads();
  if (lane == 0) {
    float s = fb2[0];
    for (int t = 0; t < 32; ++t) s = fmaf(hs[t], fw2[t], s);
    out[b] = s;
  }
}

// ---------------------------------------------------------------------------
extern "C" void kernel_launch(void* const* d_in, const int* in_sizes, int n_in,
                              void* d_out, int out_size, void* d_ws, size_t ws_size,
                              hipStream_t stream) {
  const float* feature   = (const float*)d_in[0];
  const void*  indexes   = d_in[1];
  const float* col_embed = (const float*)d_in[2];
  const float* op_embed  = (const float*)d_in[3];
  const float* w1  = (const float*)d_in[4];
  const float* b1  = (const float*)d_in[5];
  const float* w2  = (const float*)d_in[6];
  const float* b2  = (const float*)d_in[7];
  const float* w3  = (const float*)d_in[8];
  const float* b3  = (const float*)d_in[9];
  const float* fw1 = (const float*)d_in[10];
  const float* fb1 = (const float*)d_in[11];
  const float* fw2 = (const float*)d_in[12];
  const float* fb2 = (const float*)d_in[13];
  float* out = (float*)d_out;

  char* ws = (char*)d_ws;
  size_t off = 0;
  auto carve = [&](size_t bytes) -> char* {
    off = (off + 255) & ~(size_t)255;
    char* p = ws + off;
    off += bytes;
    return p;
  };
  int*    idx32   = (int*)carve((size_t)S_IDX * sizeof(int));
  short*  w1h     = (short*)carve((size_t)S_P1 * sizeof(short));
  short*  w1l     = (short*)carve((size_t)S_P1 * sizeof(short));
  short*  w2h     = (short*)carve((size_t)S_P2 * sizeof(short));
  short*  w2l     = (short*)carve((size_t)S_P2 * sizeof(short));
  short*  w3h     = (short*)carve((size_t)S_P3 * sizeof(short));
  short*  w3l     = (short*)carve((size_t)S_P3 * sizeof(short));
  float*  collate = (float*)carve((size_t)B_ * 128 * KPAD1 * sizeof(float));
  float*  Y1      = (float*)carve((size_t)B_ * 128 * 256 * sizeof(float));
  float*  Y2      = (float*)carve((size_t)B_ * 128 * 128 * sizeof(float));
  float*  Y3      = (float*)carve((size_t)B_ * 128 * 64 * sizeof(float));
  double* st1     = (double*)carve((size_t)B_ * 2 * sizeof(double));
  double* st2     = (double*)carve((size_t)B_ * 2 * sizeof(double));
  double* st3     = (double*)carve((size_t)B_ * 2 * sizeof(double));
  (void)ws_size; (void)in_sizes; (void)n_in; (void)out_size;

  constexpr int PREP_TOTAL = S_IDX + S_P1 + S_P2 + S_P3;
  hipLaunchKernelGGL(prep_kernel, dim3((PREP_TOTAL + 255) / 256), dim3(256), 0, stream,
                     indexes, idx32, w1, w1h, w1l, w2, w2h, w2l, w3, w3h, w3l);
  hipLaunchKernelGGL(embed_kernel, dim3(B_), dim3(512), 0, stream,
                     feature, col_embed, op_embed, collate);
  // conv1: K=160 in stages {96,64}, CINP 104 (13 granules, odd) -> ~55 KB
  hipLaunchKernelGGL((convm_kernel<KPAD1, 4, false, 104, 2, 96>), dim3(B_), dim3(512), 0, stream,
                     collate, idx32, w1h, w1l, b1, (const double*)nullptr, Y1, st1);
  // conv2: K=256 in 2 stages of 128, CINP 136 (17 granules, odd) -> ~71 KB
  hipLaunchKernelGGL((convm_kernel<KPAD2, 2, true, 136, 2, 128>), dim3(B_), dim3(512), 0, stream,
                     Y1, idx32, w2h, w2l, b2, st1, Y2, st2);
  // conv3: K=128, 1 stage, CINP 136 -> ~71 KB
  hipLaunchKernelGGL((convm_kernel<KPAD3, 1, true, 136, 1, 128>), dim3(B_), dim3(512), 0, stream,
                     Y2, idx32, w3h, w3l, b3, st2, Y3, st3);
  hipLaunchKernelGGL(final_kernel, dim3(B_), dim3(64), 0, stream,
                     Y3, st3, fw1, fb1, fw2, fb2, out);
}

// Round 8
// 127.800 us; speedup vs baseline: 1.3260x; 1.3260x over previous
//
#include <hip/hip_runtime.h>
#include <math.h>

// Problem constants (B, N, D) = (256, 128, 128)
#define B_    256
#define N_    128
#define MAXP  30
#define OTHER_ 35
#define CIN1  131      // real channels into conv1
#define NIDX  381      // 3*(N-1)

// conv K-geometry: KPAD per kk-region, 3 regions; fragment k-steps of 32
#define KPAD1 160
#define KPAD2 256
#define KPAD3 128
// weight-pack element counts: GKS*4wo*SUB*512
#define S_IDX (B_ * NIDX)
#define S_P1  (15 * 4 * 4 * 512)   // 122880
#define S_P2  (24 * 4 * 2 * 512)   // 98304
#define S_P3  (12 * 4 * 1 * 512)   // 24576

typedef short short8 __attribute__((ext_vector_type(8)));
typedef float f32x4 __attribute__((ext_vector_type(4)));

// RNE split of f32 into hi/lo bf16 (bit patterns as short)
__device__ inline void split1(float v, short& h, short& l) {
  unsigned u = __float_as_uint(v);
  unsigned hb = (u + 0x7fffu + ((u >> 16) & 1u)) >> 16;
  float fh = __uint_as_float(hb << 16);
  float r = v - fh;
  unsigned u2 = __float_as_uint(r);
  unsigned lb = (u2 + 0x7fffu + ((u2 >> 16) & 1u)) >> 16;
  h = (short)hb;
  l = (short)lb;
}

// ---------------------------------------------------------------------------
// Weight pack: element l -> fragment layout [gks][wo][su][lane][e], value
// w[oc][ch][kk] split into hi/lo bf16. oc=(wo*SUB+su)*16+(lane&15),
// ctot=gks*32+((lane>>4)&3)*8+e, kk=ctot/KPAD, ch=ctot%KPAD (0 if ch>=KREAL).
// ---------------------------------------------------------------------------
template <int KREAL, int KPAD, int SUB>
__device__ inline void packw(int l, const float* __restrict__ w,
                             short* __restrict__ oh, short* __restrict__ ol) {
  const int e = l & 7;
  const int lane = (l >> 3) & 63;
  const int x = l >> 9;
  const int su = x % SUB;
  const int y = x / SUB;
  const int wo = y & 3;
  const int gks = y >> 2;
  const int oc = (wo * SUB + su) * 16 + (lane & 15);
  const int ctot = gks * 32 + ((lane >> 4) & 3) * 8 + e;
  const int kk = ctot / KPAD;
  const int ch = ctot - kk * KPAD;
  const float v = (ch < KREAL) ? w[(oc * KREAL + ch) * 3 + kk] : 0.f;
  short h, lo;
  split1(v, h, lo);
  oh[l] = h;
  ol[l] = lo;
}

__global__ __launch_bounds__(256) void prep_kernel(
    const void* __restrict__ rawIdx, int* __restrict__ idx32,
    const float* __restrict__ w1, short* __restrict__ w1h, short* __restrict__ w1l,
    const float* __restrict__ w2, short* __restrict__ w2h, short* __restrict__ w2l,
    const float* __restrict__ w3, short* __restrict__ w3h, short* __restrict__ w3l) {
  const int gid = blockIdx.x * 256 + threadIdx.x;
  if (gid < S_IDX) {
    // int64 LE view is (v,0,v,0,...) with v in [0,128)
    const int* r32 = (const int*)rawIdx;
    const int lane = threadIdx.x & 63;
    const int lo = r32[2 * lane];
    const int hi = r32[2 * lane + 1];
    const bool ok = (hi == 0 && lo >= 0 && lo < N_);
    const bool is64 = __all(ok);
    idx32[gid] = is64 ? (int)((const long long*)rawIdx)[gid] : r32[gid];
  } else if (gid < S_IDX + S_P1) {
    packw<131, KPAD1, 4>(gid - S_IDX, w1, w1h, w1l);
  } else if (gid < S_IDX + S_P1 + S_P2) {
    packw<256, KPAD2, 2>(gid - (S_IDX + S_P1), w2, w2h, w2l);
  } else if (gid < S_IDX + S_P1 + S_P2 + S_P3) {
    packw<128, KPAD3, 1>(gid - (S_IDX + S_P1 + S_P2), w3, w3h, w3l);
  }
}

// ---------------------------------------------------------------------------
// Embedding + collate v3: block = (batch, node-quarter). Stage a 128x32
// feature tile (odd stride 33 -> conflict-free column reads) AND both
// embedding tables in LDS (gather loop hits LDS, not L2). 1024 blocks,
// ~45 KB LDS -> 3 blocks/CU.
// ---------------------------------------------------------------------------
__global__ __launch_bounds__(512) void embed_kernel(
    const float* __restrict__ feature,
    const float* __restrict__ col_embed,   // (200,32)
    const float* __restrict__ op_embed,    // (20,32)
    float* __restrict__ collate) {
  __shared__ float feat[128 * 33];
  __shared__ float ce[200 * 32];
  __shared__ float oe[20 * 32];
  const int b = blockIdx.x;
  const int n0 = blockIdx.y * 32;
  const int tid = threadIdx.x;
  const float* fb = feature + (size_t)b * 16384;

  // stage tables (vectorized)
  {
    const float4* s = (const float4*)col_embed;
    float4* d = (float4*)ce;
#pragma unroll
    for (int it = 0; it < 4; ++it) {
      const int t = it * 512 + tid;
      if (t < 1600) d[t] = s[t];
    }
    if (tid < 160) ((float4*)oe)[tid] = ((const float4*)op_embed)[tid];
  }
  // stage feature tile: 128 d x 32 n (each thread 8 floats of one row)
  {
    const int d = tid >> 2;
    const int c8 = (tid & 3) * 8;
    const float4 v0 = *reinterpret_cast<const float4*>(&fb[d * 128 + n0 + c8]);
    const float4 v1 = *reinterpret_cast<const float4*>(&fb[d * 128 + n0 + c8 + 4]);
    float* p = &feat[d * 33 + c8];
    p[0] = v0.x; p[1] = v0.y; p[2] = v0.z; p[3] = v0.w;
    p[4] = v1.x; p[5] = v1.y; p[6] = v1.z; p[7] = v1.w;
  }
  __syncthreads();

  const int wv = tid >> 6;
  const int lane = tid & 63;
  const int cl = lane & 31;

#pragma unroll
  for (int ni = 0; ni < 4; ++ni) {
    const int nl = wv * 4 + ni;
    const int n = n0 + nl;
    int civ = 0, oiv = 0;
    if (lane < MAXP) civ = (int)feat[(OTHER_ + lane) * 33 + nl];
    if (lane >= 32 && lane < 32 + MAXP) oiv = (int)feat[(OTHER_ + MAXP + (lane - 32)) * 33 + nl];
    const int L = (int)feat[95 * 33 + nl];

    float acc = 0.f;
    for (int i = 0; i < L; ++i) {
      const int cv = __shfl(civ, i);
      const int ov = __shfl(oiv, 32 + i);
      acc += (lane < 32) ? ce[cv * 32 + cl] : oe[ov * 32 + cl];
    }

    float* out = collate + ((size_t)b * 128 + n) * KPAD1;
    out[35 + lane] = acc;
    if (lane < 35) out[lane] = feat[lane * 33 + nl];
    if (lane < 32) out[99 + lane] = feat[(96 + lane) * 33 + nl];
    if (lane < 29) out[131 + lane] = 0.f;   // pad channels
  }
}

// ---------------------------------------------------------------------------
// MFMA tree conv v3: block = (batch, j-half) -> grid 512 = 2 blocks/CU.
// 512 threads = 8 waves (wj 0..1)x(wo 0..3); wave = 32 j (JT=2 tiles of 16)
// x SUB*16 oc. Full X staged (gathers hit any node); K split into NSTG
// stages of STG_CH ch (LDS <= ~71 KB). Odd-granule row stride (CINP/8 odd).
// Weights pre-packed fragment-order (16B/lane L2 loads). 3 MFMAs per kstep:
// xh*wh + xl*wh + xh*wl. Stats partials per (b, j-half) in f64.
// ---------------------------------------------------------------------------
template <int KPAD, int SUB, bool NORM_IN, int NCHIN, int CINP, int NSTG, int STG_CH>
__global__ __launch_bounds__(512, 2) void convm_kernel(
    const float* __restrict__ X,        // (B,128,KPAD) node-major f32
    const int* __restrict__ idx,        // (B,381)
    const short* __restrict__ wH, const short* __restrict__ wL,
    const float* __restrict__ bias,     // (COUT)
    const double* __restrict__ statsIn, // (B,NCHIN,2) or null
    float* __restrict__ Y,              // (B,128,COUT)
    double* __restrict__ statsOut) {    // (B,2,2) partials
  constexpr int KPS = KPAD / 32;
  constexpr int COUT = SUB * 64;
  constexpr int JT = 2;

  __shared__ short xhi[128 * CINP];
  __shared__ short xlo[128 * CINP];
  __shared__ int nb_s[NIDX];
  __shared__ double red[16];

  const int b = blockIdx.x;
  const int cj = blockIdx.y;       // j-half
  const int jbase = cj * 64;
  const int tid = threadIdx.x;
  const int lane = tid & 63;
  const int w = tid >> 6;
  const int wj = w >> 2;           // 0..1 (32-j half within block)
  const int wo = w & 3;            // 0..3
  const int grp = (lane >> 4) & 3;

  float mean = 0.f, inv = 1.f;
  if (NORM_IN) {
    double S = 0.0, Q = 0.0;
#pragma unroll
    for (int i = 0; i < NCHIN; ++i) {
      S += statsIn[(b * NCHIN + i) * 2];
      Q += statsIn[(b * NCHIN + i) * 2 + 1];
    }
    const double cnt = (double)KPAD * 128.0;
    const double m = S / cnt;
    double var = (Q - S * S / cnt) / (cnt - 1.0);
    if (var < 0.0) var = 0.0;
    mean = (float)m;
    inv = (float)(1.0 / (sqrt(var) + 1e-5));
  }

  const float* __restrict__ Xb = X + (size_t)b * (128 * KPAD);
  const short8* __restrict__ wH8 = (const short8*)wH;
  const short8* __restrict__ wL8 = (const short8*)wL;

  int nbr[JT][3];
  f32x4 acc[JT][SUB];
#pragma unroll
  for (int jt = 0; jt < JT; ++jt)
#pragma unroll
    for (int su = 0; su < SUB; ++su) {
      acc[jt][su][0] = 0.f; acc[jt][su][1] = 0.f;
      acc[jt][su][2] = 0.f; acc[jt][su][3] = 0.f;
    }

#pragma unroll
  for (int s = 0; s < NSTG; ++s) {
    const int chb = s * STG_CH;
    const int chn = (KPAD - chb < STG_CH) ? (KPAD - chb) : STG_CH;
    const int PKs = chn / 8;
    if (s > 0) __syncthreads();
    for (int t = tid; t < 128 * PKs; t += 512) {
      const int n = t / PKs;
      const int ch0 = chb + (t - n * PKs) * 8;
      const float4 a0 = *reinterpret_cast<const float4*>(&Xb[n * KPAD + ch0]);
      const float4 a1 = *reinterpret_cast<const float4*>(&Xb[n * KPAD + ch0 + 4]);
      float vv[8] = {a0.x, a0.y, a0.z, a0.w, a1.x, a1.y, a1.z, a1.w};
      short8 h8, l8;
#pragma unroll
      for (int i = 0; i < 8; ++i) {
        float v = vv[i];
        if (NORM_IN) {
          v = (v - mean) * inv;
          v = (v > 0.f) ? v : 0.01f * v;
        }
        short h, l;
        split1(v, h, l);
        h8[i] = h;
        l8[i] = l;
      }
      const int ei = n * CINP + (ch0 - chb);
      *reinterpret_cast<short8*>(&xhi[ei]) = h8;
      *reinterpret_cast<short8*>(&xlo[ei]) = l8;
    }
    if (s == 0 && tid < NIDX) nb_s[tid] = idx[b * NIDX + tid];
    __syncthreads();

    if (s == 0) {
#pragma unroll
      for (int jt = 0; jt < JT; ++jt) {
        const int j = jbase + wj * 32 + jt * 16 + (lane & 15);
#pragma unroll
        for (int kk = 0; kk < 3; ++kk)
          nbr[jt][kk] = (j > 0) ? nb_s[(j - 1) * 3 + kk] : 0;
      }
    }

    const int ks_lo = chb / 32;
    const int ks_hi = (chb + chn) / 32;
#pragma unroll
    for (int kk = 0; kk < 3; ++kk) {
#pragma unroll 2
      for (int ks = ks_lo; ks < ks_hi; ++ks) {
        const int gks = kk * KPS + ks;
        short8 bh[SUB], bl[SUB];
#pragma unroll
        for (int su = 0; su < SUB; ++su) {
          const int wi = ((gks * 4 + wo) * SUB + su) * 64 + lane;
          bh[su] = wH8[wi];
          bl[su] = wL8[wi];
        }
        const int ch_off = ks * 32 - chb + grp * 8;
#pragma unroll
        for (int jt = 0; jt < JT; ++jt) {
          const int ei = nbr[jt][kk] * CINP + ch_off;
          const short8 ah = *reinterpret_cast<const short8*>(&xhi[ei]);
          const short8 al = *reinterpret_cast<const short8*>(&xlo[ei]);
#pragma unroll
          for (int su = 0; su < SUB; ++su) {
            acc[jt][su] = __builtin_amdgcn_mfma_f32_16x16x32_bf16(ah, bh[su], acc[jt][su], 0, 0, 0);
            acc[jt][su] = __builtin_amdgcn_mfma_f32_16x16x32_bf16(al, bh[su], acc[jt][su], 0, 0, 0);
            acc[jt][su] = __builtin_amdgcn_mfma_f32_16x16x32_bf16(ah, bl[su], acc[jt][su], 0, 0, 0);
          }
        }
      }
    }
  }

  // ---- epilogue: bias, zero col, store, f64 stats ----
  double s_sum = 0.0, s_sq = 0.0;
#pragma unroll
  for (int su = 0; su < SUB; ++su) {
    const int oc = (wo * SUB + su) * 16 + (lane & 15);
    const float bv = bias[oc];
#pragma unroll
    for (int jt = 0; jt < JT; ++jt) {
#pragma unroll
      for (int r = 0; r < 4; ++r) {
        const int j = jbase + wj * 32 + jt * 16 + grp * 4 + r;
        const float val = (j > 0) ? acc[jt][su][r] + bv : 0.f;
        Y[((size_t)b * 128 + j) * COUT + oc] = val;
        s_sum += (double)val;
        s_sq += (double)val * (double)val;
      }
    }
  }

#pragma unroll
  for (int o = 32; o > 0; o >>= 1) {
    s_sum += __shfl_down(s_sum, o, 64);
    s_sq  += __shfl_down(s_sq, o, 64);
  }
  if (lane == 0) { red[w * 2] = s_sum; red[w * 2 + 1] = s_sq; }
  __syncthreads();
  if (tid == 0) {
    double S = 0.0, Q = 0.0;
#pragma unroll
    for (int i = 0; i < 8; ++i) { S += red[i * 2]; Q += red[i * 2 + 1]; }
    statsOut[(b * 2 + cj) * 2] = S;
    statsOut[(b * 2 + cj) * 2 + 1] = Q;
  }
}

// ---------------------------------------------------------------------------
// Final: combine conv3 stats partials (2), normalize, maxpool, 2-layer MLP.
// ---------------------------------------------------------------------------
__global__ __launch_bounds__(64) void final_kernel(
    const float* __restrict__ Y3,      // (B,128,64)
    const double* __restrict__ st,     // (B,2,2)
    const float* __restrict__ fw1,     // (32,64)
    const float* __restrict__ fb1,     // (32)
    const float* __restrict__ fw2,     // (1,32)
    const float* __restrict__ fb2,     // (1)
    float* __restrict__ out) {
  const int b = blockIdx.x;
  const int lane = threadIdx.x;

  const double S = st[(b * 2) * 2] + st[(b * 2 + 1) * 2];
  const double Q = st[(b * 2) * 2 + 1] + st[(b * 2 + 1) * 2 + 1];
  const double cnt = 64.0 * 128.0;
  const double m = S / cnt;
  double var = (Q - S * S / cnt) / (cnt - 1.0);
  if (var < 0.0) var = 0.0;
  const float mean = (float)m;
  const float inv = (float)(1.0 / (sqrt(var) + 1e-5));

  const float* Yb = Y3 + (size_t)b * 128 * 64;
  float mx = -3.4e38f;
  for (int n = 0; n < 128; ++n) {
    const float v = (Yb[n * 64 + lane] - mean) * inv;
    mx = fmaxf(mx, v);
  }
  __shared__ float pooled[64];
  __shared__ float hs[32];
  pooled[lane] = mx;
  __syncthreads();
  if (lane < 32) {
    float a = fb1[lane];
    for (int c = 0; c < 64; ++c) a = fmaf(pooled[c], fw1[lane * 64 + c], a);
    hs[lane] = fmaxf(a, 0.f);
  }
  __syncthreads();
  if (lane == 0) {
    float s = fb2[0];
    for (int t = 0; t < 32; ++t) s = fmaf(hs[t], fw2[t], s);
    out[b] = s;
  }
}

// ---------------------------------------------------------------------------
extern "C" void kernel_launch(void* const* d_in, const int* in_sizes, int n_in,
                              void* d_out, int out_size, void* d_ws, size_t ws_size,
                              hipStream_t stream) {
  const float* feature   = (const float*)d_in[0];
  const void*  indexes   = d_in[1];
  const float* col_embed = (const float*)d_in[2];
  const float* op_embed  = (const float*)d_in[3];
  const float* w1  = (const float*)d_in[4];
  const float* b1  = (const float*)d_in[5];
  const float* w2  = (const float*)d_in[6];
  const float* b2  = (const float*)d_in[7];
  const float* w3  = (const float*)d_in[8];
  const float* b3  = (const float*)d_in[9];
  const float* fw1 = (const float*)d_in[10];
  const float* fb1 = (const float*)d_in[11];
  const float* fw2 = (const float*)d_in[12];
  const float* fb2 = (const float*)d_in[13];
  float* out = (float*)d_out;

  char* ws = (char*)d_ws;
  size_t off = 0;
  auto carve = [&](size_t bytes) -> char* {
    off = (off + 255) & ~(size_t)255;
    char* p = ws + off;
    off += bytes;
    return p;
  };
  int*    idx32   = (int*)carve((size_t)S_IDX * sizeof(int));
  short*  w1h     = (short*)carve((size_t)S_P1 * sizeof(short));
  short*  w1l     = (short*)carve((size_t)S_P1 * sizeof(short));
  short*  w2h     = (short*)carve((size_t)S_P2 * sizeof(short));
  short*  w2l     = (short*)carve((size_t)S_P2 * sizeof(short));
  short*  w3h     = (short*)carve((size_t)S_P3 * sizeof(short));
  short*  w3l     = (short*)carve((size_t)S_P3 * sizeof(short));
  float*  collate = (float*)carve((size_t)B_ * 128 * KPAD1 * sizeof(float));
  float*  Y1      = (float*)carve((size_t)B_ * 128 * 256 * sizeof(float));
  float*  Y2      = (float*)carve((size_t)B_ * 128 * 128 * sizeof(float));
  float*  Y3      = (float*)carve((size_t)B_ * 128 * 64 * sizeof(float));
  double* st1     = (double*)carve((size_t)B_ * 2 * 2 * sizeof(double));
  double* st2     = (double*)carve((size_t)B_ * 2 * 2 * sizeof(double));
  double* st3     = (double*)carve((size_t)B_ * 2 * 2 * sizeof(double));
  (void)ws_size; (void)in_sizes; (void)n_in; (void)out_size;

  constexpr int PREP_TOTAL = S_IDX + S_P1 + S_P2 + S_P3;
  hipLaunchKernelGGL(prep_kernel, dim3((PREP_TOTAL + 255) / 256), dim3(256), 0, stream,
                     indexes, idx32, w1, w1h, w1l, w2, w2h, w2l, w3, w3h, w3l);
  hipLaunchKernelGGL(embed_kernel, dim3(B_, 4), dim3(512), 0, stream,
                     feature, col_embed, op_embed, collate);
  // conv1: K=160 staged {96,64}, CINP 104 (13 granules) ~55 KB, 2 j-halves
  hipLaunchKernelGGL((convm_kernel<KPAD1, 4, false, 1, 104, 2, 96>),
                     dim3(B_, 2), dim3(512), 0, stream,
                     collate, idx32, w1h, w1l, b1, (const double*)nullptr, Y1, st1);
  // conv2: K=256 staged {128,128}, CINP 136 (17 granules) ~71 KB, 2 j-halves
  hipLaunchKernelGGL((convm_kernel<KPAD2, 2, true, 2, 136, 2, 128>),
                     dim3(B_, 2), dim3(512), 0, stream,
                     Y1, idx32, w2h, w2l, b2, st1, Y2, st2);
  // conv3: K=128 single stage, CINP 136 ~71 KB, 2 j-halves
  hipLaunchKernelGGL((convm_kernel<KPAD3, 1, true, 2, 136, 1, 128>),
                     dim3(B_, 2), dim3(512), 0, stream,
                     Y2, idx32, w3h, w3l, b3, st2, Y3, st3);
  hipLaunchKernelGGL(final_kernel, dim3(B_), dim3(64), 0, stream,
                     Y3, st3, fw1, fb1, fw2, fb2, out);
}